// Round 8
// baseline (1115.522 us; speedup 1.0000x reference)
//
#include <hip/hip_runtime.h>

#define DEV __device__ __forceinline__

// ---------------- coupling-tensor storage (row-major [i][j][k]) ----------------
#define OFF444 0
#define OFF464 729
#define OFF644 1782
#define OFF664 2835
#define OFF446 4356
#define OFF466 5409
#define OFF646 6930
#define OFF666 8451
#define OFF424 10648
#define OFF624 11053
#define OFF426 11638
#define OFF626 12223
#define NC_TOT 13068

__device__ float gC[NC_TOT];
__device__ float gSH[24];        // [p][comp] 4 x 6 : col0 = y0, cols1..5 = y2
__device__ float gX[16384 * 22]; // static scratch for x (H=W=128)

__device__ const int gL1t[12] = {4,4,6,6,4,4,6,6,4,6,4,6};
__device__ const int gL2t[12] = {4,6,4,6,4,6,4,6,2,2,2,2};
__device__ const int gL3t[12] = {4,4,4,4,6,6,6,6,4,4,6,6};
__device__ const int gOFFt[12]= {OFF444,OFF464,OFF644,OFF664,OFF446,OFF466,OFF646,OFF666,
                                 OFF424,OFF624,OFF426,OFF626};

// ---------------- init: LITERAL transcription of the reference ----------------
DEV double dfact(int n){ double r = 1.0; for(int i = 2; i <= n; ++i) r *= (double)i; return r; }

DEV double su2_cg(const double* F, int j1,int m1,int j2,int m2,int j3,int m3){
  if(m1 + m2 != m3) return 0.0;
  int vmin = -j1 + j2 + m3;
  if(-j1 + m1 > vmin) vmin = -j1 + m1;
  if(0 > vmin) vmin = 0;
  int vmax = j2 + j3 + m1;
  if(j3 - j1 + j2 < vmax) vmax = j3 - j1 + j2;
  if(j3 + m3 < vmax) vmax = j3 + m3;
  if(vmax < vmin) return 0.0;
  double c = sqrt((2.0*j3 + 1.0) * F[j3+j1-j2] * F[j3-j1+j2] * F[j1+j2-j3] / F[j1+j2+j3+1]);
  c *= sqrt(F[j3+m3]*F[j3-m3]*F[j1-m1]*F[j1+m1]*F[j2-m2]*F[j2+m2]);
  double s = 0.0;
  for(int v = vmin; v <= vmax; ++v){
    double term = F[j2+j3+m1-v]*F[j1-m1+v] /
                  (F[v]*F[j3-j1+j2-v]*F[j3+m3-v]*F[v+j1-j2-m3]);
    s += ((v + j2 + m2) & 1) ? -term : term;
  }
  return c * s;
}

// q_l[row i][col j] including the (-1j)^l factor
DEV void qentry(int l, int i, int j, double& outr, double& outi){
  const double s = 0.70710678118654752440;
  int m = i - l;
  double ar = 0.0, ai = 0.0;
  if(m < 0){
    if(j == l - m) ar = s;
    else if(j == l + m) ai = -s;
  } else if(m == 0){
    if(j == l) ar = 1.0;
  } else {
    double sg = (m & 1) ? -1.0 : 1.0;
    if(j == l + m) ar = sg * s;
    else if(j == l - m) ai = sg * s;
  }
  int lm = l & 3; // multiply by (-i)^l
  if(lm == 0){ outr = ar;  outi = ai;  }
  else if(lm == 1){ outr = ai;  outi = -ar; }
  else if(lm == 2){ outr = -ar; outi = -ai; }
  else { outr = -ai; outi = ar; }
}

__global__ __launch_bounds__(256) void init_w3j(){
  __shared__ double F[24];
  __shared__ double red[256];
  __shared__ double s_scale;
  const int tid = threadIdx.x;
  if(tid < 24) F[tid] = dfact(tid);
  __syncthreads();
  const int b  = blockIdx.x;
  if(b == 0 && tid == 0){
    const double PI = 3.14159265358979323846;
    const double sv = 0.70710678118654752440;
    double dx[4] = {-sv, sv, -sv, sv};
    double dy[4] = {-sv, -sv, sv, sv};
    double kk = 0.5 * sqrt(15.0 / PI);
    for(int p = 0; p < 4; ++p){
      double x = dx[p], y = dy[p], z = 0.0;
      gSH[p*6+0] = (float)(0.5 / sqrt(PI));
      gSH[p*6+1] = (float)(kk * x * y);
      gSH[p*6+2] = (float)(kk * y * z);
      gSH[p*6+3] = (float)(0.25 * sqrt(5.0 / PI) * (3.0*z*z - 1.0));
      gSH[p*6+4] = (float)(kk * z * x);
      gSH[p*6+5] = (float)(0.5 * kk * (x*x - y*y));
    }
  }
  const int l1 = gL1t[b], l2 = gL2t[b], l3 = gL3t[b];
  const int d2 = 2*l2 + 1, d3 = 2*l3 + 1;
  const int total = (2*l1+1) * d2 * d3;
  const int off = gOFFt[b];
  double ss = 0.0;
  for(int t = tid; t < total; t += 256){
    int mo = t % d3; int r = t / d3; int lo = r % d2; int jo = r / d2;
    double acc = 0.0;
    for(int i = 0; i <= 2*l1; ++i){
      double q1r, q1i; qentry(l1, i, jo, q1r, q1i);
      if(q1r == 0.0 && q1i == 0.0) continue;
      for(int k = 0; k <= 2*l2; ++k){
        double q2r, q2i; qentry(l2, k, lo, q2r, q2i);
        if(q2r == 0.0 && q2i == 0.0) continue;
        double r12 = q1r*q2r - q1i*q2i;
        double i12 = q1r*q2i + q1i*q2r;
        for(int n = 0; n <= 2*l3; ++n){
          double q3r, q3i; qentry(l3, n, mo, q3r, q3i);
          if(q3r == 0.0 && q3i == 0.0) continue;
          double cg = su2_cg(F, l1, i-l1, l2, k-l2, l3, n-l3);
          if(cg == 0.0) continue;
          acc += (r12*q3r + i12*q3i) * cg;  // Re[(q1*q2)*conj(q3)] * cg
        }
      }
    }
    gC[off + t] = (float)acc;
    ss += acc * acc;
  }
  red[tid] = ss;
  __syncthreads();
  for(int stp = 128; stp > 0; stp >>= 1){
    if(tid < stp) red[tid] += red[tid + stp];
    __syncthreads();
  }
  if(tid == 0) s_scale = 1.0 / sqrt(red[0]);
  __syncthreads();
  float sc = (float)s_scale;
  for(int t = tid; t < total; t += 256) gC[off + t] *= sc;
}

// ---------------- tp_ff core (shared by stage A and B) ----------------
DEV void tp_ff_core(const float* __restrict__ pa4, const float* __restrict__ pa6,
                    const float* b4, const float* b6, const float* sw,
                    float* o4, float* o6){
  const float* __restrict__ C = gC;
  #pragma unroll 1
  for(int i = 0; i < 9; ++i){
    float ai = pa4[i];
    const float* __restrict__ c444 = C + OFF444 + i*81;
    const float* __restrict__ c446 = C + OFF446 + i*117;
    const float* __restrict__ c464 = C + OFF464 + i*117;
    const float* __restrict__ c466 = C + OFF466 + i*169;
    #pragma unroll
    for(int j = 0; j < 9; ++j){
      float t = ai * b4[j]; float t4 = t * sw[0]; float t6 = t * sw[4];
      #pragma unroll
      for(int k = 0; k < 9; ++k)  o4[k] = fmaf(c444[j*9 + k],  t4, o4[k]);
      #pragma unroll
      for(int k = 0; k < 13; ++k) o6[k] = fmaf(c446[j*13 + k], t6, o6[k]);
    }
    #pragma unroll
    for(int j = 0; j < 13; ++j){
      float t = ai * b6[j]; float t4 = t * sw[1]; float t6 = t * sw[5];
      #pragma unroll
      for(int k = 0; k < 9; ++k)  o4[k] = fmaf(c464[j*9 + k],  t4, o4[k]);
      #pragma unroll
      for(int k = 0; k < 13; ++k) o6[k] = fmaf(c466[j*13 + k], t6, o6[k]);
    }
  }
  #pragma unroll 1
  for(int i = 0; i < 13; ++i){
    float ai = pa6[i];
    const float* __restrict__ c644 = C + OFF644 + i*81;
    const float* __restrict__ c646 = C + OFF646 + i*117;
    const float* __restrict__ c664 = C + OFF664 + i*117;
    const float* __restrict__ c666 = C + OFF666 + i*169;
    #pragma unroll
    for(int j = 0; j < 9; ++j){
      float t = ai * b4[j]; float t4 = t * sw[2]; float t6 = t * sw[6];
      #pragma unroll
      for(int k = 0; k < 9; ++k)  o4[k] = fmaf(c644[j*9 + k],  t4, o4[k]);
      #pragma unroll
      for(int k = 0; k < 13; ++k) o6[k] = fmaf(c646[j*13 + k], t6, o6[k]);
    }
    #pragma unroll
    for(int j = 0; j < 13; ++j){
      float t = ai * b6[j]; float t4 = t * sw[3]; float t6 = t * sw[7];
      #pragma unroll
      for(int k = 0; k < 9; ++k)  o4[k] = fmaf(c664[j*9 + k],  t4, o4[k]);
      #pragma unroll
      for(int k = 0; k < 13; ++k) o6[k] = fmaf(c666[j*13 + k], t6, o6[k]);
    }
  }
}

// ---------------- stage A: spatial 3x3 + tp_ff residual on low-res ----------------
__global__ __launch_bounds__(256) void stage_a(
    const float* __restrict__ f4, const float* __restrict__ f6,
    const int* __restrict__ pH, const int* __restrict__ pW,
    const float* __restrict__ spw, const float* __restrict__ wsp,
    float* __restrict__ xws, int useg, int N){
  int n = blockIdx.x * 256 + threadIdx.x;
  if(n >= N) return;
  int H = *pH, W = *pW;
  int i = n / W, j = n - i * W;
  float nb[22];
  #pragma unroll
  for(int c = 0; c < 22; ++c) nb[c] = 0.f;
  #pragma unroll
  for(int di = 0; di < 3; ++di){
    int ip = i + di - 1; ip = ip < 0 ? 0 : (ip >= H ? H - 1 : ip);
    #pragma unroll
    for(int dj = 0; dj < 3; ++dj){
      int jp = j + dj - 1; jp = jp < 0 ? 0 : (jp >= W ? W - 1 : jp);
      float wg = spw[di*3 + dj];
      const float* q4 = f4 + (ip * W + jp) * 9;
      const float* q6 = f6 + (ip * W + jp) * 13;
      #pragma unroll
      for(int c = 0; c < 9; ++c)  nb[c]     = fmaf(wg, q4[c], nb[c]);
      #pragma unroll
      for(int c = 0; c < 13; ++c) nb[9 + c] = fmaf(wg, q6[c], nb[9 + c]);
    }
  }
  float sw[8];
  #pragma unroll
  for(int t = 0; t < 4; ++t) sw[t] = 1.5f * wsp[t];
  #pragma unroll
  for(int t = 4; t < 8; ++t) sw[t] = 1.80277563773199465f * wsp[t]; // sqrt(13)/2
  float o4[9], o6[13];
  #pragma unroll
  for(int k = 0; k < 9; ++k)  o4[k] = 0.f;
  #pragma unroll
  for(int k = 0; k < 13; ++k) o6[k] = 0.f;
  tp_ff_core(f4 + n*9, f6 + n*13, nb, nb + 9, sw, o4, o6);
  float* xo = (useg ? gX : xws) + n * 22;
  #pragma unroll
  for(int k = 0; k < 9; ++k)  xo[k]     = f4[n*9 + k]  + o4[k];
  #pragma unroll
  for(int k = 0; k < 13; ++k) xo[9 + k] = f6[n*13 + k] + o6[k];
}

// ---------------- stage B: upsample + literal SH aggregation + tp_ff residual ----------------
// OUTPUT IS FLOAT32 (reference returns float32; harness: "else float*").
__global__ __launch_bounds__(256) void stage_b(
    const float* __restrict__ xws, int useg,
    const int* __restrict__ pH, const int* __restrict__ pW,
    const float* __restrict__ wagg, const float* __restrict__ wtp,
    float* __restrict__ out, int Nr){
  int n = blockIdx.x * 256 + threadIdx.x;
  if(n >= Nr) return;
  const float* __restrict__ x = useg ? gX : xws;
  int H = *pH, W = *pW;
  int Hr = H * 4, Wr = W * 4;
  int ir = n / Wr, jr = n - ir * Wr;
  int il = ir >> 2, jl = jr >> 2;
  int il2 = (ir + 1 >= Hr ? Hr - 1 : ir + 1) >> 2;
  int jl2 = (jr + 1 >= Wr ? Wr - 1 : jr + 1) >> 2;
  const float* __restrict__ p0 = x + (il  * W + jl ) * 22;
  const float* __restrict__ p1 = x + (il  * W + jl2) * 22;
  const float* __restrict__ p2 = x + (il2 * W + jl ) * 22;
  const float* __restrict__ p3 = x + (il2 * W + jl2) * 22;

  const float SQ3   = 1.73205080756887729f;
  const float SQ133 = 2.08166599946613263f;   // sqrt(13/3)
  const float RS13  = 0.27735009811261457f;   // 1/sqrt(13)

  float sh0v[4], sh2v[4][5];
  #pragma unroll
  for(int p = 0; p < 4; ++p){
    sh0v[p] = gSH[p*6];
    #pragma unroll
    for(int j = 0; j < 5; ++j) sh2v[p][j] = gSH[p*6 + 1 + j];
  }
  float w0 = wagg[0], w1 = wagg[1], w2 = wagg[2], w3 = wagg[3], w4 = wagg[4], w5 = wagg[5];
  float c4e0 = SQ3 * (1.0f/3.0f) * w0;
  float c6e0 = SQ133 * RS13 * w4;
  float c41 = SQ3 * w1,   c42 = SQ3 * w2;
  float c63 = SQ133 * w3, c65 = SQ133 * w5;

  float ctx4[9], ctx6[13];
  #pragma unroll
  for(int k = 0; k < 9; ++k)  ctx4[k] = 0.f;
  #pragma unroll
  for(int k = 0; k < 13; ++k) ctx6[k] = 0.f;
  const float* __restrict__ C = gC;

  // literal: out4 = sqrt3*(w0*E0(a4)/3 + w1*Ep(a4,C424) + w2*Ep(a6,C624))
  //          out6 = sqrt(13/3)*(w3*Ep(a4,C426) + w4*E0(a6)/sqrt13 + w5*Ep(a6,C626))
  #pragma unroll 1
  for(int i = 0; i < 9; ++i){
    float a0 = p0[i], a1 = p1[i], a2 = p2[i], a3 = p3[i];
    float m0 = a0*sh0v[0] + a1*sh0v[1] + a2*sh0v[2] + a3*sh0v[3];
    ctx4[i] += c4e0 * m0;
    #pragma unroll
    for(int j = 0; j < 5; ++j){
      float m = a0*sh2v[0][j] + a1*sh2v[1][j] + a2*sh2v[2][j] + a3*sh2v[3][j];
      float f1 = c41 * m, f3 = c63 * m;
      const float* __restrict__ cA = C + OFF424 + (i*5 + j)*9;
      const float* __restrict__ cB = C + OFF426 + (i*5 + j)*13;
      #pragma unroll
      for(int k = 0; k < 9; ++k)  ctx4[k] = fmaf(f1, cA[k], ctx4[k]);
      #pragma unroll
      for(int k = 0; k < 13; ++k) ctx6[k] = fmaf(f3, cB[k], ctx6[k]);
    }
  }
  #pragma unroll 1
  for(int i = 0; i < 13; ++i){
    float a0 = p0[9+i], a1 = p1[9+i], a2 = p2[9+i], a3 = p3[9+i];
    float m0 = a0*sh0v[0] + a1*sh0v[1] + a2*sh0v[2] + a3*sh0v[3];
    ctx6[i] += c6e0 * m0;
    #pragma unroll
    for(int j = 0; j < 5; ++j){
      float m = a0*sh2v[0][j] + a1*sh2v[1][j] + a2*sh2v[2][j] + a3*sh2v[3][j];
      float f2 = c42 * m, f5 = c65 * m;
      const float* __restrict__ cA = C + OFF624 + (i*5 + j)*9;
      const float* __restrict__ cB = C + OFF626 + (i*5 + j)*13;
      #pragma unroll
      for(int k = 0; k < 9; ++k)  ctx4[k] = fmaf(f2, cA[k], ctx4[k]);
      #pragma unroll
      for(int k = 0; k < 13; ++k) ctx6[k] = fmaf(f5, cB[k], ctx6[k]);
    }
  }

  float sw[8];
  #pragma unroll
  for(int t = 0; t < 4; ++t) sw[t] = 1.5f * wtp[t];
  #pragma unroll
  for(int t = 4; t < 8; ++t) sw[t] = 1.80277563773199465f * wtp[t]; // sqrt(13)/2
  float o4[9], o6[13];
  #pragma unroll
  for(int k = 0; k < 9; ++k)  o4[k] = 0.f;
  #pragma unroll
  for(int k = 0; k < 13; ++k) o6[k] = 0.f;
  tp_ff_core(p0, p0 + 9, ctx4, ctx6, sw, o4, o6);

  float* out4 = out + (size_t)n * 9;
  float* out6 = out + (size_t)Nr * 9 + (size_t)n * 13;
  #pragma unroll
  for(int k = 0; k < 9; ++k)  out4[k] = o4[k] + p0[k];
  #pragma unroll
  for(int k = 0; k < 13; ++k) out6[k] = o6[k] + p0[9 + k];
}

extern "C" void kernel_launch(void* const* d_in, const int* in_sizes, int n_in,
                              void* d_out, int out_size, void* d_ws, size_t ws_size,
                              hipStream_t stream){
  const float* f4   = (const float*)d_in[0];
  const float* f6   = (const float*)d_in[1];
  const int*   pH   = (const int*)d_in[2];
  const int*   pW   = (const int*)d_in[3];
  const float* spw  = (const float*)d_in[4];
  const float* wsp  = (const float*)d_in[5];
  const float* wagg = (const float*)d_in[6];
  const float* wtp  = (const float*)d_in[7];
  int N  = in_sizes[0] / 9;   // H*W
  int Nr = N * 16;            // (4H)*(4W)
  int useg = (N <= 16384) ? 1 : 0;
  float* x = (float*)d_ws;

  hipLaunchKernelGGL(init_w3j, dim3(12), dim3(256), 0, stream);
  hipLaunchKernelGGL(stage_a, dim3((N + 255)/256), dim3(256), 0, stream,
                     f4, f6, pH, pW, spw, wsp, x, useg, N);
  hipLaunchKernelGGL(stage_b, dim3((Nr + 255)/256), dim3(256), 0, stream,
                     x, useg, pH, pW, wagg, wtp, (float*)d_out, Nr);
}

// Round 9
// 347.095 us; speedup vs baseline: 3.2139x; 3.2139x over previous
//
#include <hip/hip_runtime.h>

#define DEV __device__ __forceinline__

// ---------------- coupling-tensor storage (row-major [i][j][k]) ----------------
#define OFF444 0
#define OFF464 729
#define OFF644 1782
#define OFF664 2835
#define OFF446 4356
#define OFF466 5409
#define OFF646 6930
#define OFF666 8451
#define OFF424 10648
#define OFF624 11053
#define OFF426 11638
#define OFF626 12223
#define NC_TOT 13068

__device__ float gC[NC_TOT];
__device__ float gSH[24];        // [p][comp] 4 x 6 : col0 = y0, cols1..5 = y2
__device__ float gX[16384 * 22]; // static scratch for x (H=W=128)

__device__ const int gL1t[12] = {4,4,6,6,4,4,6,6,4,6,4,6};
__device__ const int gL2t[12] = {4,6,4,6,4,6,4,6,2,2,2,2};
__device__ const int gL3t[12] = {4,4,4,4,6,6,6,6,4,4,6,6};
__device__ const int gOFFt[12]= {OFF444,OFF464,OFF644,OFF664,OFF446,OFF466,OFF646,OFF666,
                                 OFF424,OFF624,OFF426,OFF626};

// ---------------- init ----------------
DEV double dfact(int n){ double r = 1.0; for(int i = 2; i <= n; ++i) r *= (double)i; return r; }

DEV double su2_cg(const double* F, int j1,int m1,int j2,int m2,int j3,int m3){
  if(m1 + m2 != m3) return 0.0;
  int vmin = -j1 + j2 + m3;
  if(-j1 + m1 > vmin) vmin = -j1 + m1;
  if(0 > vmin) vmin = 0;
  int vmax = j2 + j3 + m1;
  if(j3 - j1 + j2 < vmax) vmax = j3 - j1 + j2;
  if(j3 + m3 < vmax) vmax = j3 + m3;
  if(vmax < vmin) return 0.0;
  double c = sqrt((2.0*j3 + 1.0) * F[j3+j1-j2] * F[j3-j1+j2] * F[j1+j2-j3] / F[j1+j2+j3+1]);
  c *= sqrt(F[j3+m3]*F[j3-m3]*F[j1-m1]*F[j1+m1]*F[j2-m2]*F[j2+m2]);
  double s = 0.0;
  for(int v = vmin; v <= vmax; ++v){
    double term = F[j2+j3+m1-v]*F[j1-m1+v] /
                  (F[v]*F[j3-j1+j2-v]*F[j3+m3-v]*F[v+j1-j2-m3]);
    s += ((v + j2 + m2) & 1) ? -term : term;
  }
  return c * s;
}

// q_l[row i][col j] including the (-1j)^l factor
DEV void qentry(int l, int i, int j, double& outr, double& outi){
  const double s = 0.70710678118654752440;
  int m = i - l;
  double ar = 0.0, ai = 0.0;
  if(m < 0){
    if(j == l - m) ar = s;
    else if(j == l + m) ai = -s;
  } else if(m == 0){
    if(j == l) ar = 1.0;
  } else {
    double sg = (m & 1) ? -1.0 : 1.0;
    if(j == l + m) ar = sg * s;
    else if(j == l - m) ai = sg * s;
  }
  int lm = l & 3; // multiply by (-i)^l
  if(lm == 0){ outr = ar;  outi = ai;  }
  else if(lm == 1){ outr = ai;  outi = -ar; }
  else if(lm == 2){ outr = -ar; outi = -ai; }
  else { outr = -ai; outi = ar; }
}

// Sparse enumeration: q-column jo has nonzero rows only at {jo, 2l-jo}
// (r1 vs r2 produced bit-identical results -> equivalence HW-verified).
__global__ __launch_bounds__(256) void init_w3j(){
  __shared__ double F[24];
  __shared__ double red[256];
  __shared__ double s_scale;
  const int tid = threadIdx.x;
  if(tid < 24) F[tid] = dfact(tid);
  __syncthreads();
  const int b  = blockIdx.x;
  if(b == 0 && tid == 0){
    const double PI = 3.14159265358979323846;
    const double sv = 0.70710678118654752440;
    double dx[4] = {-sv, sv, -sv, sv};
    double dy[4] = {-sv, -sv, sv, sv};
    double kk = 0.5 * sqrt(15.0 / PI);
    for(int p = 0; p < 4; ++p){
      double x = dx[p], y = dy[p], z = 0.0;
      gSH[p*6+0] = (float)(0.5 / sqrt(PI));
      gSH[p*6+1] = (float)(kk * x * y);
      gSH[p*6+2] = (float)(kk * y * z);
      gSH[p*6+3] = (float)(0.25 * sqrt(5.0 / PI) * (3.0*z*z - 1.0));
      gSH[p*6+4] = (float)(kk * z * x);
      gSH[p*6+5] = (float)(0.5 * kk * (x*x - y*y));
    }
  }
  const int l1 = gL1t[b], l2 = gL2t[b], l3 = gL3t[b];
  const int d2 = 2*l2 + 1, d3 = 2*l3 + 1;
  const int total = (2*l1+1) * d2 * d3;
  const int off = gOFFt[b];
  double ss = 0.0;
  for(int t = tid; t < total; t += 256){
    int mo = t % d3; int r = t / d3; int lo = r % d2; int jo = r / d2;
    int ci[2]; int ni = 1; ci[0] = jo; if(jo != 2*l1 - jo){ ci[1] = 2*l1 - jo; ni = 2; }
    int ck[2]; int nk = 1; ck[0] = lo; if(lo != 2*l2 - lo){ ck[1] = 2*l2 - lo; nk = 2; }
    int cn[2]; int nn = 1; cn[0] = mo; if(mo != 2*l3 - mo){ cn[1] = 2*l3 - mo; nn = 2; }
    double acc = 0.0;
    for(int a = 0; a < ni; ++a){
      int i = ci[a];
      double q1r, q1i; qentry(l1, i, jo, q1r, q1i);
      if(q1r == 0.0 && q1i == 0.0) continue;
      for(int bq = 0; bq < nk; ++bq){
        int k = ck[bq];
        double q2r, q2i; qentry(l2, k, lo, q2r, q2i);
        if(q2r == 0.0 && q2i == 0.0) continue;
        double r12 = q1r*q2r - q1i*q2i;
        double i12 = q1r*q2i + q1i*q2r;
        for(int cq = 0; cq < nn; ++cq){
          int n = cn[cq];
          double q3r, q3i; qentry(l3, n, mo, q3r, q3i);
          if(q3r == 0.0 && q3i == 0.0) continue;
          double cg = su2_cg(F, l1, i-l1, l2, k-l2, l3, n-l3);
          if(cg == 0.0) continue;
          acc += (r12*q3r + i12*q3i) * cg;  // Re[(q1*q2)*conj(q3)] * cg
        }
      }
    }
    gC[off + t] = (float)acc;
    ss += acc * acc;
  }
  red[tid] = ss;
  __syncthreads();
  for(int stp = 128; stp > 0; stp >>= 1){
    if(tid < stp) red[tid] += red[tid + stp];
    __syncthreads();
  }
  if(tid == 0) s_scale = 1.0 / sqrt(red[0]);
  __syncthreads();
  float sc = (float)s_scale;
  for(int t = tid; t < total; t += 256) gC[off + t] *= sc;
}

// ---------------- tp_ff core (LDS-resident C) ----------------
DEV void tp_ff_core(const float* __restrict__ sC,
                    const float* __restrict__ pa4, const float* __restrict__ pa6,
                    const float* b4, const float* b6, const float* sw,
                    float* o4, float* o6){
  #pragma unroll 1
  for(int i = 0; i < 9; ++i){
    float ai = pa4[i];
    const float* __restrict__ c444 = sC + OFF444 + i*81;
    const float* __restrict__ c446 = sC + OFF446 + i*117;
    const float* __restrict__ c464 = sC + OFF464 + i*117;
    const float* __restrict__ c466 = sC + OFF466 + i*169;
    #pragma unroll
    for(int j = 0; j < 9; ++j){
      float t = ai * b4[j]; float t4 = t * sw[0]; float t6 = t * sw[4];
      #pragma unroll
      for(int k = 0; k < 9; ++k)  o4[k] = fmaf(c444[j*9 + k],  t4, o4[k]);
      #pragma unroll
      for(int k = 0; k < 13; ++k) o6[k] = fmaf(c446[j*13 + k], t6, o6[k]);
    }
    #pragma unroll
    for(int j = 0; j < 13; ++j){
      float t = ai * b6[j]; float t4 = t * sw[1]; float t6 = t * sw[5];
      #pragma unroll
      for(int k = 0; k < 9; ++k)  o4[k] = fmaf(c464[j*9 + k],  t4, o4[k]);
      #pragma unroll
      for(int k = 0; k < 13; ++k) o6[k] = fmaf(c466[j*13 + k], t6, o6[k]);
    }
  }
  #pragma unroll 1
  for(int i = 0; i < 13; ++i){
    float ai = pa6[i];
    const float* __restrict__ c644 = sC + OFF644 + i*81;
    const float* __restrict__ c646 = sC + OFF646 + i*117;
    const float* __restrict__ c664 = sC + OFF664 + i*117;
    const float* __restrict__ c666 = sC + OFF666 + i*169;
    #pragma unroll
    for(int j = 0; j < 9; ++j){
      float t = ai * b4[j]; float t4 = t * sw[2]; float t6 = t * sw[6];
      #pragma unroll
      for(int k = 0; k < 9; ++k)  o4[k] = fmaf(c644[j*9 + k],  t4, o4[k]);
      #pragma unroll
      for(int k = 0; k < 13; ++k) o6[k] = fmaf(c646[j*13 + k], t6, o6[k]);
    }
    #pragma unroll
    for(int j = 0; j < 13; ++j){
      float t = ai * b6[j]; float t4 = t * sw[3]; float t6 = t * sw[7];
      #pragma unroll
      for(int k = 0; k < 9; ++k)  o4[k] = fmaf(c664[j*9 + k],  t4, o4[k]);
      #pragma unroll
      for(int k = 0; k < 13; ++k) o6[k] = fmaf(c666[j*13 + k], t6, o6[k]);
    }
  }
}

// ---------------- stage A: spatial 3x3 + tp_ff residual on low-res ----------------
__global__ __launch_bounds__(256) void stage_a(
    const float* __restrict__ f4, const float* __restrict__ f6,
    const int* __restrict__ pH, const int* __restrict__ pW,
    const float* __restrict__ spw, const float* __restrict__ wsp,
    float* __restrict__ xws, int useg, int N){
  __shared__ float sC[NC_TOT];
  for(int t = threadIdx.x; t < NC_TOT; t += 256) sC[t] = gC[t];
  __syncthreads();
  int n = blockIdx.x * 256 + threadIdx.x;
  if(n >= N) return;
  int H = *pH, W = *pW;
  int i = n / W, j = n - i * W;
  float nb[22];
  #pragma unroll
  for(int c = 0; c < 22; ++c) nb[c] = 0.f;
  #pragma unroll
  for(int di = 0; di < 3; ++di){
    int ip = i + di - 1; ip = ip < 0 ? 0 : (ip >= H ? H - 1 : ip);
    #pragma unroll
    for(int dj = 0; dj < 3; ++dj){
      int jp = j + dj - 1; jp = jp < 0 ? 0 : (jp >= W ? W - 1 : jp);
      float wg = spw[di*3 + dj];
      const float* q4 = f4 + (ip * W + jp) * 9;
      const float* q6 = f6 + (ip * W + jp) * 13;
      #pragma unroll
      for(int c = 0; c < 9; ++c)  nb[c]     = fmaf(wg, q4[c], nb[c]);
      #pragma unroll
      for(int c = 0; c < 13; ++c) nb[9 + c] = fmaf(wg, q6[c], nb[9 + c]);
    }
  }
  float sw[8];
  #pragma unroll
  for(int t = 0; t < 4; ++t) sw[t] = 1.5f * wsp[t];
  #pragma unroll
  for(int t = 4; t < 8; ++t) sw[t] = 1.80277563773199465f * wsp[t]; // sqrt(13)/2
  float o4[9], o6[13];
  #pragma unroll
  for(int k = 0; k < 9; ++k)  o4[k] = 0.f;
  #pragma unroll
  for(int k = 0; k < 13; ++k) o6[k] = 0.f;
  tp_ff_core(sC, f4 + n*9, f6 + n*13, nb, nb + 9, sw, o4, o6);
  float* xo = (useg ? gX : xws) + n * 22;
  #pragma unroll
  for(int k = 0; k < 9; ++k)  xo[k]     = f4[n*9 + k]  + o4[k];
  #pragma unroll
  for(int k = 0; k < 13; ++k) xo[9 + k] = f6[n*13 + k] + o6[k];
}

// ---------------- stage B: one thread per (coarse cell, variant) ----------------
// Within a 4x4 cell, (p0..p3) take only 4 distinct values, selected by
// (bi = ir%4==3, bj = jr%4==3); ff = x_cell for all 16 pixels. Compute the 4
// variants (pointer-identical math to the verified per-pixel form) and fan out.
__global__ __launch_bounds__(256) void stage_b(
    const float* __restrict__ xws, int useg,
    const int* __restrict__ pH, const int* __restrict__ pW,
    const float* __restrict__ wagg, const float* __restrict__ wtp,
    float* __restrict__ out, int N){
  __shared__ float sC[NC_TOT];
  for(int t = threadIdx.x; t < NC_TOT; t += 256) sC[t] = gC[t];
  __syncthreads();
  int n2 = blockIdx.x * 256 + threadIdx.x;
  if(n2 >= 4*N) return;
  const float* __restrict__ x = useg ? gX : xws;
  int H = *pH, W = *pW;
  int Wr = W * 4;
  int cell = n2 >> 2, v = n2 & 3;
  int il = cell / W, jl = cell - il * W;
  int bi = v >> 1, bj = v & 1;
  int il2 = bi ? (il + 1 < H ? il + 1 : H - 1) : il;
  int jl2 = bj ? (jl + 1 < W ? jl + 1 : W - 1) : jl;
  const float* __restrict__ p0 = x + (il  * W + jl ) * 22;
  const float* __restrict__ p1 = x + (il  * W + jl2) * 22;
  const float* __restrict__ p2 = x + (il2 * W + jl ) * 22;
  const float* __restrict__ p3 = x + (il2 * W + jl2) * 22;

  const float SQ3   = 1.73205080756887729f;
  const float SQ133 = 2.08166599946613263f;   // sqrt(13/3)
  const float RS13  = 0.27735009811261457f;   // 1/sqrt(13)

  float sh0v[4], sh2v[4][5];
  #pragma unroll
  for(int p = 0; p < 4; ++p){
    sh0v[p] = gSH[p*6];
    #pragma unroll
    for(int j = 0; j < 5; ++j) sh2v[p][j] = gSH[p*6 + 1 + j];
  }
  float w0 = wagg[0], w1 = wagg[1], w2 = wagg[2], w3 = wagg[3], w4 = wagg[4], w5 = wagg[5];
  float c4e0 = SQ3 * (1.0f/3.0f) * w0;
  float c6e0 = SQ133 * RS13 * w4;
  float c41 = SQ3 * w1,   c42 = SQ3 * w2;
  float c63 = SQ133 * w3, c65 = SQ133 * w5;

  float ctx4[9], ctx6[13];
  #pragma unroll
  for(int k = 0; k < 9; ++k)  ctx4[k] = 0.f;
  #pragma unroll
  for(int k = 0; k < 13; ++k) ctx6[k] = 0.f;

  #pragma unroll 1
  for(int i = 0; i < 9; ++i){
    float a0 = p0[i], a1 = p1[i], a2 = p2[i], a3 = p3[i];
    float m0 = a0*sh0v[0] + a1*sh0v[1] + a2*sh0v[2] + a3*sh0v[3];
    ctx4[i] += c4e0 * m0;
    #pragma unroll
    for(int j = 0; j < 5; ++j){
      float m = a0*sh2v[0][j] + a1*sh2v[1][j] + a2*sh2v[2][j] + a3*sh2v[3][j];
      float f1 = c41 * m, f3 = c63 * m;
      const float* __restrict__ cA = sC + OFF424 + (i*5 + j)*9;
      const float* __restrict__ cB = sC + OFF426 + (i*5 + j)*13;
      #pragma unroll
      for(int k = 0; k < 9; ++k)  ctx4[k] = fmaf(f1, cA[k], ctx4[k]);
      #pragma unroll
      for(int k = 0; k < 13; ++k) ctx6[k] = fmaf(f3, cB[k], ctx6[k]);
    }
  }
  #pragma unroll 1
  for(int i = 0; i < 13; ++i){
    float a0 = p0[9+i], a1 = p1[9+i], a2 = p2[9+i], a3 = p3[9+i];
    float m0 = a0*sh0v[0] + a1*sh0v[1] + a2*sh0v[2] + a3*sh0v[3];
    ctx6[i] += c6e0 * m0;
    #pragma unroll
    for(int j = 0; j < 5; ++j){
      float m = a0*sh2v[0][j] + a1*sh2v[1][j] + a2*sh2v[2][j] + a3*sh2v[3][j];
      float f2 = c42 * m, f5 = c65 * m;
      const float* __restrict__ cA = sC + OFF624 + (i*5 + j)*9;
      const float* __restrict__ cB = sC + OFF626 + (i*5 + j)*13;
      #pragma unroll
      for(int k = 0; k < 9; ++k)  ctx4[k] = fmaf(f2, cA[k], ctx4[k]);
      #pragma unroll
      for(int k = 0; k < 13; ++k) ctx6[k] = fmaf(f5, cB[k], ctx6[k]);
    }
  }

  float sw[8];
  #pragma unroll
  for(int t = 0; t < 4; ++t) sw[t] = 1.5f * wtp[t];
  #pragma unroll
  for(int t = 4; t < 8; ++t) sw[t] = 1.80277563773199465f * wtp[t]; // sqrt(13)/2
  float o4[9], o6[13];
  #pragma unroll
  for(int k = 0; k < 9; ++k)  o4[k] = 0.f;
  #pragma unroll
  for(int k = 0; k < 13; ++k) o6[k] = 0.f;
  tp_ff_core(sC, p0, p0 + 9, ctx4, ctx6, sw, o4, o6);

  float r4[9], r6[13];
  #pragma unroll
  for(int k = 0; k < 9; ++k)  r4[k] = o4[k] + p0[k];
  #pragma unroll
  for(int k = 0; k < 13; ++k) r6[k] = o6[k] + p0[9 + k];

  // fan out to this variant's pixels: rows bi?{3}:{0,1,2}, cols bj?{3}:{0,1,2}
  size_t Nr = (size_t)N * 16;
  int r0 = bi ? 3 : 0, rcnt = bi ? 1 : 3;
  int c0 = bj ? 3 : 0, ccnt = bj ? 1 : 3;
  for(int dr = 0; dr < rcnt; ++dr){
    int ir = il*4 + r0 + dr;
    for(int dc = 0; dc < ccnt; ++dc){
      int jr = jl*4 + c0 + dc;
      size_t np = (size_t)ir * Wr + jr;
      float* out4 = out + np * 9;
      float* out6 = out + Nr * 9 + np * 13;
      #pragma unroll
      for(int k = 0; k < 9; ++k)  out4[k] = r4[k];
      #pragma unroll
      for(int k = 0; k < 13; ++k) out6[k] = r6[k];
    }
  }
}

extern "C" void kernel_launch(void* const* d_in, const int* in_sizes, int n_in,
                              void* d_out, int out_size, void* d_ws, size_t ws_size,
                              hipStream_t stream){
  const float* f4   = (const float*)d_in[0];
  const float* f6   = (const float*)d_in[1];
  const int*   pH   = (const int*)d_in[2];
  const int*   pW   = (const int*)d_in[3];
  const float* spw  = (const float*)d_in[4];
  const float* wsp  = (const float*)d_in[5];
  const float* wagg = (const float*)d_in[6];
  const float* wtp  = (const float*)d_in[7];
  int N  = in_sizes[0] / 9;   // H*W
  int useg = (N <= 16384) ? 1 : 0;
  float* x = (float*)d_ws;

  hipLaunchKernelGGL(init_w3j, dim3(12), dim3(256), 0, stream);
  hipLaunchKernelGGL(stage_a, dim3((N + 255)/256), dim3(256), 0, stream,
                     f4, f6, pH, pW, spw, wsp, x, useg, N);
  hipLaunchKernelGGL(stage_b, dim3((4*N + 255)/256), dim3(256), 0, stream,
                     x, useg, pH, pW, wagg, wtp, (float*)d_out, N);
}

// Round 10
// 280.118 us; speedup vs baseline: 3.9823x; 1.2391x over previous
//
#include <hip/hip_runtime.h>

#define DEV __device__ __forceinline__

// ---------------- coupling-tensor storage (row-major [i][j][k]) ----------------
#define OFF444 0
#define OFF464 729
#define OFF644 1782
#define OFF664 2835
#define OFF446 4356
#define OFF466 5409
#define OFF646 6930
#define OFF666 8451
#define OFF424 10648
#define OFF624 11053
#define OFF426 11638
#define OFF626 12223
#define NC_TOT 13068

__device__ __align__(16) float gC[NC_TOT];
__device__ float gSH[24];        // [p][comp] 4 x 6 : col0 = y0, cols1..5 = y2
__device__ float gX[16384 * 22]; // static scratch for x (H=W=128)

__device__ const int gL1t[12] = {4,4,6,6,4,4,6,6,4,6,4,6};
__device__ const int gL2t[12] = {4,6,4,6,4,6,4,6,2,2,2,2};
__device__ const int gL3t[12] = {4,4,4,4,6,6,6,6,4,4,6,6};
__device__ const int gOFFt[12]= {OFF444,OFF464,OFF644,OFF664,OFF446,OFF466,OFF646,OFF666,
                                 OFF424,OFF624,OFF426,OFF626};

// ---------------- init ----------------
DEV double dfact(int n){ double r = 1.0; for(int i = 2; i <= n; ++i) r *= (double)i; return r; }

DEV double su2_cg(const double* F, int j1,int m1,int j2,int m2,int j3,int m3){
  if(m1 + m2 != m3) return 0.0;
  int vmin = -j1 + j2 + m3;
  if(-j1 + m1 > vmin) vmin = -j1 + m1;
  if(0 > vmin) vmin = 0;
  int vmax = j2 + j3 + m1;
  if(j3 - j1 + j2 < vmax) vmax = j3 - j1 + j2;
  if(j3 + m3 < vmax) vmax = j3 + m3;
  if(vmax < vmin) return 0.0;
  double c = sqrt((2.0*j3 + 1.0) * F[j3+j1-j2] * F[j3-j1+j2] * F[j1+j2-j3] / F[j1+j2+j3+1]);
  c *= sqrt(F[j3+m3]*F[j3-m3]*F[j1-m1]*F[j1+m1]*F[j2-m2]*F[j2+m2]);
  double s = 0.0;
  for(int v = vmin; v <= vmax; ++v){
    double term = F[j2+j3+m1-v]*F[j1-m1+v] /
                  (F[v]*F[j3-j1+j2-v]*F[j3+m3-v]*F[v+j1-j2-m3]);
    s += ((v + j2 + m2) & 1) ? -term : term;
  }
  return c * s;
}

// q_l[row i][col j] including the (-1j)^l factor
DEV void qentry(int l, int i, int j, double& outr, double& outi){
  const double s = 0.70710678118654752440;
  int m = i - l;
  double ar = 0.0, ai = 0.0;
  if(m < 0){
    if(j == l - m) ar = s;
    else if(j == l + m) ai = -s;
  } else if(m == 0){
    if(j == l) ar = 1.0;
  } else {
    double sg = (m & 1) ? -1.0 : 1.0;
    if(j == l + m) ar = sg * s;
    else if(j == l - m) ai = sg * s;
  }
  int lm = l & 3; // multiply by (-i)^l
  if(lm == 0){ outr = ar;  outi = ai;  }
  else if(lm == 1){ outr = ai;  outi = -ar; }
  else if(lm == 2){ outr = -ar; outi = -ai; }
  else { outr = -ai; outi = ar; }
}

// Sparse enumeration (r1 vs r2 bit-identical -> equivalence HW-verified).
__global__ __launch_bounds__(1024) void init_w3j(){
  __shared__ double F[24];
  __shared__ double red[1024];
  __shared__ double s_scale;
  const int tid = threadIdx.x;
  if(tid < 24) F[tid] = dfact(tid);
  __syncthreads();
  const int b  = blockIdx.x;
  if(b == 0 && tid == 0){
    const double PI = 3.14159265358979323846;
    const double sv = 0.70710678118654752440;
    double dx[4] = {-sv, sv, -sv, sv};
    double dy[4] = {-sv, -sv, sv, sv};
    double kk = 0.5 * sqrt(15.0 / PI);
    for(int p = 0; p < 4; ++p){
      double x = dx[p], y = dy[p], z = 0.0;
      gSH[p*6+0] = (float)(0.5 / sqrt(PI));
      gSH[p*6+1] = (float)(kk * x * y);
      gSH[p*6+2] = (float)(kk * y * z);
      gSH[p*6+3] = (float)(0.25 * sqrt(5.0 / PI) * (3.0*z*z - 1.0));
      gSH[p*6+4] = (float)(kk * z * x);
      gSH[p*6+5] = (float)(0.5 * kk * (x*x - y*y));
    }
  }
  const int l1 = gL1t[b], l2 = gL2t[b], l3 = gL3t[b];
  const int d2 = 2*l2 + 1, d3 = 2*l3 + 1;
  const int total = (2*l1+1) * d2 * d3;
  const int off = gOFFt[b];
  double ss = 0.0;
  for(int t = tid; t < total; t += 1024){
    int mo = t % d3; int r = t / d3; int lo = r % d2; int jo = r / d2;
    int ci[2]; int ni = 1; ci[0] = jo; if(jo != 2*l1 - jo){ ci[1] = 2*l1 - jo; ni = 2; }
    int ck[2]; int nk = 1; ck[0] = lo; if(lo != 2*l2 - lo){ ck[1] = 2*l2 - lo; nk = 2; }
    int cn[2]; int nn = 1; cn[0] = mo; if(mo != 2*l3 - mo){ cn[1] = 2*l3 - mo; nn = 2; }
    double acc = 0.0;
    for(int a = 0; a < ni; ++a){
      int i = ci[a];
      double q1r, q1i; qentry(l1, i, jo, q1r, q1i);
      if(q1r == 0.0 && q1i == 0.0) continue;
      for(int bq = 0; bq < nk; ++bq){
        int k = ck[bq];
        double q2r, q2i; qentry(l2, k, lo, q2r, q2i);
        if(q2r == 0.0 && q2i == 0.0) continue;
        double r12 = q1r*q2r - q1i*q2i;
        double i12 = q1r*q2i + q1i*q2r;
        for(int cq = 0; cq < nn; ++cq){
          int n = cn[cq];
          double q3r, q3i; qentry(l3, n, mo, q3r, q3i);
          if(q3r == 0.0 && q3i == 0.0) continue;
          double cg = su2_cg(F, l1, i-l1, l2, k-l2, l3, n-l3);
          if(cg == 0.0) continue;
          acc += (r12*q3r + i12*q3i) * cg;  // Re[(q1*q2)*conj(q3)] * cg
        }
      }
    }
    gC[off + t] = (float)acc;
    ss += acc * acc;
  }
  red[tid] = ss;
  __syncthreads();
  for(int stp = 512; stp > 0; stp >>= 1){
    if(tid < stp) red[tid] += red[tid + stp];
    __syncthreads();
  }
  if(tid == 0) s_scale = 1.0 / sqrt(red[0]);
  __syncthreads();
  float sc = (float)s_scale;
  for(int t = tid; t < total; t += 1024) gC[off + t] *= sc;
}

// ---------------- quad-split tp_ff core ----------------
// 4 lanes (quad) split the 22-row i-dimension; butterfly leaves full o4/o6 in
// every lane. Caller must keep quads intact (guards drop whole quads).
DEV void tp_quad(const float* __restrict__ sC, int lane,
                 const float* __restrict__ a4, const float* __restrict__ a6,
                 const float* b4, const float* b6, const float* sw,
                 float* o4, float* o6){
  for(int ii = lane; ii < 22; ii += 4){
    const bool is4 = ii < 9;
    const int il = is4 ? ii : ii - 9;
    const float ai = is4 ? a4[il] : a6[il];
    const float* __restrict__ cA4 = sC + (is4 ? OFF444 + il*81  : OFF644 + il*81);
    const float* __restrict__ cA6 = sC + (is4 ? OFF446 + il*117 : OFF646 + il*117);
    const float* __restrict__ cB4 = sC + (is4 ? OFF464 + il*117 : OFF664 + il*117);
    const float* __restrict__ cB6 = sC + (is4 ? OFF466 + il*169 : OFF666 + il*169);
    const float s4a = is4 ? sw[0] : sw[2];
    const float s6a = is4 ? sw[4] : sw[6];
    const float s4b = is4 ? sw[1] : sw[3];
    const float s6b = is4 ? sw[5] : sw[7];
    #pragma unroll
    for(int j = 0; j < 9; ++j){
      float t = ai * b4[j]; float t4 = t * s4a, t6 = t * s6a;
      #pragma unroll
      for(int k = 0; k < 9; ++k)  o4[k] = fmaf(cA4[j*9 + k],  t4, o4[k]);
      #pragma unroll
      for(int k = 0; k < 13; ++k) o6[k] = fmaf(cA6[j*13 + k], t6, o6[k]);
    }
    #pragma unroll
    for(int j = 0; j < 13; ++j){
      float t = ai * b6[j]; float t4 = t * s4b, t6 = t * s6b;
      #pragma unroll
      for(int k = 0; k < 9; ++k)  o4[k] = fmaf(cB4[j*9 + k],  t4, o4[k]);
      #pragma unroll
      for(int k = 0; k < 13; ++k) o6[k] = fmaf(cB6[j*13 + k], t6, o6[k]);
    }
  }
  #pragma unroll
  for(int k = 0; k < 9; ++k){
    o4[k] += __shfl_xor(o4[k], 1);
    o4[k] += __shfl_xor(o4[k], 2);
  }
  #pragma unroll
  for(int k = 0; k < 13; ++k){
    o6[k] += __shfl_xor(o6[k], 1);
    o6[k] += __shfl_xor(o6[k], 2);
  }
}

// ---------------- stage A: 4 lanes per pixel ----------------
__global__ __launch_bounds__(256) void stage_a(
    const float* __restrict__ f4, const float* __restrict__ f6,
    const int* __restrict__ pH, const int* __restrict__ pW,
    const float* __restrict__ spw, const float* __restrict__ wsp,
    float* __restrict__ xws, int useg, int N){
  __shared__ __align__(16) float sC[NC_TOT];
  {
    float4* s4p = (float4*)sC;
    const float4* g4p = (const float4*)gC;
    for(int t = threadIdx.x; t < NC_TOT/4; t += 256) s4p[t] = g4p[t];
  }
  __syncthreads();
  int gid = blockIdx.x * 256 + threadIdx.x;
  int n = gid >> 2, lane = gid & 3;
  if(n >= N) return;
  int H = *pH, W = *pW;
  int i = n / W, j = n - i * W;
  float nb[22];
  #pragma unroll
  for(int c = 0; c < 22; ++c) nb[c] = 0.f;
  #pragma unroll
  for(int di = 0; di < 3; ++di){
    int ip = i + di - 1; ip = ip < 0 ? 0 : (ip >= H ? H - 1 : ip);
    #pragma unroll
    for(int dj = 0; dj < 3; ++dj){
      int jp = j + dj - 1; jp = jp < 0 ? 0 : (jp >= W ? W - 1 : jp);
      float wg = spw[di*3 + dj];
      const float* q4 = f4 + (ip * W + jp) * 9;
      const float* q6 = f6 + (ip * W + jp) * 13;
      #pragma unroll
      for(int c = 0; c < 9; ++c)  nb[c]     = fmaf(wg, q4[c], nb[c]);
      #pragma unroll
      for(int c = 0; c < 13; ++c) nb[9 + c] = fmaf(wg, q6[c], nb[9 + c]);
    }
  }
  float sw[8];
  #pragma unroll
  for(int t = 0; t < 4; ++t) sw[t] = 1.5f * wsp[t];
  #pragma unroll
  for(int t = 4; t < 8; ++t) sw[t] = 1.80277563773199465f * wsp[t]; // sqrt(13)/2
  float o4[9], o6[13];
  #pragma unroll
  for(int k = 0; k < 9; ++k)  o4[k] = 0.f;
  #pragma unroll
  for(int k = 0; k < 13; ++k) o6[k] = 0.f;
  tp_quad(sC, lane, f4 + n*9, f6 + n*13, nb, nb + 9, sw, o4, o6);
  float* xo = (useg ? gX : xws) + n * 22;
  for(int k = lane; k < 9; k += 4)  xo[k]     = f4[n*9 + k]  + o4[k];
  for(int k = lane; k < 13; k += 4) xo[9 + k] = f6[n*13 + k] + o6[k];
}

// ---------------- stage B: 4 lanes per (cell, variant) ----------------
__global__ __launch_bounds__(256) void stage_b(
    const float* __restrict__ xws, int useg,
    const int* __restrict__ pH, const int* __restrict__ pW,
    const float* __restrict__ wagg, const float* __restrict__ wtp,
    float* __restrict__ out, int N){
  __shared__ __align__(16) float sC[NC_TOT];
  {
    float4* s4p = (float4*)sC;
    const float4* g4p = (const float4*)gC;
    for(int t = threadIdx.x; t < NC_TOT/4; t += 256) s4p[t] = g4p[t];
  }
  __syncthreads();
  int gid = blockIdx.x * 256 + threadIdx.x;
  int t2 = gid >> 2, lane = gid & 3;
  if(t2 >= 4*N) return;
  const float* __restrict__ x = useg ? gX : xws;
  int H = *pH, W = *pW;
  int Wr = W * 4;
  int cell = t2 >> 2, v = t2 & 3;
  int il = cell / W, jl = cell - il * W;
  int bi = v >> 1, bj = v & 1;
  int il2 = bi ? (il + 1 < H ? il + 1 : H - 1) : il;
  int jl2 = bj ? (jl + 1 < W ? jl + 1 : W - 1) : jl;
  const float* __restrict__ p0 = x + (il  * W + jl ) * 22;
  const float* __restrict__ p1 = x + (il  * W + jl2) * 22;
  const float* __restrict__ p2 = x + (il2 * W + jl ) * 22;
  const float* __restrict__ p3 = x + (il2 * W + jl2) * 22;

  const float SQ3   = 1.73205080756887729f;
  const float SQ133 = 2.08166599946613263f;   // sqrt(13/3)
  const float RS13  = 0.27735009811261457f;   // 1/sqrt(13)

  float sh0v[4], sh2v[4][5];
  #pragma unroll
  for(int p = 0; p < 4; ++p){
    sh0v[p] = gSH[p*6];
    #pragma unroll
    for(int j = 0; j < 5; ++j) sh2v[p][j] = gSH[p*6 + 1 + j];
  }
  float w0 = wagg[0], w1 = wagg[1], w2 = wagg[2], w3 = wagg[3], w4 = wagg[4], w5 = wagg[5];
  float c4e0 = SQ3 * (1.0f/3.0f) * w0;
  float c6e0 = SQ133 * RS13 * w4;
  float c41 = SQ3 * w1,   c42 = SQ3 * w2;
  float c63 = SQ133 * w3, c65 = SQ133 * w5;

  // quad-split context accumulation (i-rows split across lanes, butterfly after)
  float ctx4[9], ctx6[13];
  #pragma unroll
  for(int k = 0; k < 9; ++k)  ctx4[k] = 0.f;
  #pragma unroll
  for(int k = 0; k < 13; ++k) ctx6[k] = 0.f;
  for(int ii = lane; ii < 22; ii += 4){
    const bool is4 = ii < 9;
    const int ilr = is4 ? ii : ii - 9;
    float a0 = p0[ii], a1 = p1[ii], a2 = p2[ii], a3 = p3[ii];
    float m0 = a0*sh0v[0] + a1*sh0v[1] + a2*sh0v[2] + a3*sh0v[3];
    if(is4) ctx4[ilr] += c4e0 * m0; else ctx6[ilr] += c6e0 * m0;
    const float* __restrict__ cA = sC + (is4 ? OFF424 + ilr*45 : OFF624 + ilr*45);
    const float* __restrict__ cB = sC + (is4 ? OFF426 + ilr*65 : OFF626 + ilr*65);
    const float fA = is4 ? c41 : c42;
    const float fB = is4 ? c63 : c65;
    #pragma unroll
    for(int j = 0; j < 5; ++j){
      float m = a0*sh2v[0][j] + a1*sh2v[1][j] + a2*sh2v[2][j] + a3*sh2v[3][j];
      float f1 = fA * m, f3 = fB * m;
      #pragma unroll
      for(int k = 0; k < 9; ++k)  ctx4[k] = fmaf(f1, cA[j*9 + k], ctx4[k]);
      #pragma unroll
      for(int k = 0; k < 13; ++k) ctx6[k] = fmaf(f3, cB[j*13 + k], ctx6[k]);
    }
  }
  #pragma unroll
  for(int k = 0; k < 9; ++k){
    ctx4[k] += __shfl_xor(ctx4[k], 1);
    ctx4[k] += __shfl_xor(ctx4[k], 2);
  }
  #pragma unroll
  for(int k = 0; k < 13; ++k){
    ctx6[k] += __shfl_xor(ctx6[k], 1);
    ctx6[k] += __shfl_xor(ctx6[k], 2);
  }

  float sw[8];
  #pragma unroll
  for(int t = 0; t < 4; ++t) sw[t] = 1.5f * wtp[t];
  #pragma unroll
  for(int t = 4; t < 8; ++t) sw[t] = 1.80277563773199465f * wtp[t]; // sqrt(13)/2
  float o4[9], o6[13];
  #pragma unroll
  for(int k = 0; k < 9; ++k)  o4[k] = 0.f;
  #pragma unroll
  for(int k = 0; k < 13; ++k) o6[k] = 0.f;
  tp_quad(sC, lane, p0, p0 + 9, ctx4, ctx6, sw, o4, o6);

  // fan out: rows bi?{3}:{0,1,2}, cols bj?{3}:{0,1,2}; lanes split k
  size_t Nr = (size_t)N * 16;
  int r0 = bi ? 3 : 0, rcnt = bi ? 1 : 3;
  int c0 = bj ? 3 : 0, ccnt = bj ? 1 : 3;
  for(int dr = 0; dr < rcnt; ++dr){
    int ir = il*4 + r0 + dr;
    for(int dc = 0; dc < ccnt; ++dc){
      int jr = jl*4 + c0 + dc;
      size_t np = (size_t)ir * Wr + jr;
      float* out4 = out + np * 9;
      float* out6 = out + Nr * 9 + np * 13;
      for(int k = lane; k < 9; k += 4)  out4[k] = o4[k] + p0[k];
      for(int k = lane; k < 13; k += 4) out6[k] = o6[k] + p0[9 + k];
    }
  }
}

extern "C" void kernel_launch(void* const* d_in, const int* in_sizes, int n_in,
                              void* d_out, int out_size, void* d_ws, size_t ws_size,
                              hipStream_t stream){
  const float* f4   = (const float*)d_in[0];
  const float* f6   = (const float*)d_in[1];
  const int*   pH   = (const int*)d_in[2];
  const int*   pW   = (const int*)d_in[3];
  const float* spw  = (const float*)d_in[4];
  const float* wsp  = (const float*)d_in[5];
  const float* wagg = (const float*)d_in[6];
  const float* wtp  = (const float*)d_in[7];
  int N  = in_sizes[0] / 9;   // H*W
  int useg = (N <= 16384) ? 1 : 0;
  float* x = (float*)d_ws;

  hipLaunchKernelGGL(init_w3j, dim3(12), dim3(1024), 0, stream);
  hipLaunchKernelGGL(stage_a, dim3((4*N + 255)/256), dim3(256), 0, stream,
                     f4, f6, pH, pW, spw, wsp, x, useg, N);
  hipLaunchKernelGGL(stage_b, dim3((16*N + 255)/256), dim3(256), 0, stream,
                     x, useg, pH, pW, wagg, wtp, (float*)d_out, N);
}